// Round 2
// baseline (3112.403 us; speedup 1.0000x reference)
//
#include <hip/hip_runtime.h>
#include <math.h>

typedef _Float16 h16;
typedef h16 half4v __attribute__((ext_vector_type(4)));
typedef h16 half2v __attribute__((ext_vector_type(2)));

#define HH 512
#define WW 512
#define BB 8
#define NPIX (HH*WW)        // 262144
#define NTOT (BB*NPIX)      // 2097152
#define ITER 50

#define TX 64
#define TY 16

#define BLK_PER_BATCH 256
#define PART_ITER_STRIDE (BB*BLK_PER_BATCH*8)   // 16384 floats per iteration
#define SCAL_STRIDE (BB*8)                      // 64 floats per iteration

// Gaussian 5x5 (sigma=5)
constexpr double W0d = 0.92311634638663587;  // exp(-0.08)
constexpr double W1d = 0.98019867330675525;  // exp(-0.02)
constexpr double SUM1D = 1.0 + 2.0*(W0d + W1d);
constexpr float  INV_NORM = (float)(1.0/(SUM1D*SUM1D + 1e-15));
constexpr float  W0f = (float)W0d;
constexpr float  W1f = (float)W1d;
constexpr float  S1f = (float)SUM1D;

// fast sigmoid: v_exp + v_rcp (1-2 ulp; fp16 state noise dominates)
__device__ __forceinline__ float fast_sigmoid(float x) {
    const float e = __expf(-x);
    return __builtin_amdgcn_rcpf(1.0f + e);
}

__device__ __forceinline__ float edge1d(int v) {
    float r = S1f;
    if (v == 0 || v == HH - 1) r = S1f - W0f - W1f;
    else if (v == 1 || v == HH - 2) r = S1f - W0f;
    return r;
}

// Wave reduce {s0,sy,syy} over the 16-lane tx-groups first (all lanes of a
// 16-group share x), build the 6 x-weighted channels once, then combine the
// 4 groups: 24 shfl instead of 36. Cross-wave combine via LDS; thread 0
// stores the 8-float partial slot, fences, and bumps the per-batch counter.
// Returns true (block-uniform) iff this block was the last of its batch.
__device__ __forceinline__ bool tail_reduce6(float s0, float sy, float syy, float x,
                                             float* __restrict__ dst8,
                                             unsigned* __restrict__ cnt) {
    #pragma unroll
    for (int m = 1; m < 16; m <<= 1) {
        s0  += __shfl_xor(s0,  m, 64);
        sy  += __shfl_xor(sy,  m, 64);
        syy += __shfl_xor(syy, m, 64);
    }
    float v0 = s0, v1 = x * s0, v2 = sy, v3 = x * sy, v4 = x * x * s0, v5 = syy;
    #pragma unroll
    for (int m = 16; m < 64; m <<= 1) {
        v0 += __shfl_xor(v0, m, 64);
        v1 += __shfl_xor(v1, m, 64);
        v2 += __shfl_xor(v2, m, 64);
        v3 += __shfl_xor(v3, m, 64);
        v4 += __shfl_xor(v4, m, 64);
        v5 += __shfl_xor(v5, m, 64);
    }
    __shared__ float sm[4][6];
    __shared__ int smLast;
    const int wv = threadIdx.x >> 6;
    if ((threadIdx.x & 63) == 0) {
        sm[wv][0] = v0; sm[wv][1] = v1; sm[wv][2] = v2;
        sm[wv][3] = v3; sm[wv][4] = v4; sm[wv][5] = v5;
    }
    __syncthreads();
    if (threadIdx.x == 0) {
        float t0 = sm[0][0] + sm[1][0] + sm[2][0] + sm[3][0];
        float t1 = sm[0][1] + sm[1][1] + sm[2][1] + sm[3][1];
        float t2 = sm[0][2] + sm[1][2] + sm[2][2] + sm[3][2];
        float t3 = sm[0][3] + sm[1][3] + sm[2][3] + sm[3][3];
        float t4 = sm[0][4] + sm[1][4] + sm[2][4] + sm[3][4];
        float t5 = sm[0][5] + sm[1][5] + sm[2][5] + sm[3][5];
        *(float4*)dst8       = make_float4(t0, t1, t2, t3);
        *(float4*)(dst8 + 4) = make_float4(t4, t5, 0.f, 0.f);
        __threadfence();                       // release partials device-wide
        smLast = (atomicAdd(cnt, 1u) == (unsigned)(BLK_PER_BATCH - 1)) ? 1 : 0;
    }
    __syncthreads();
    return smLast != 0;
}

// One wave reduces this batch's 256 partial slots and writes the 5 scalars
// the NEXT iteration needs: {cx, cy, cossin, bsin, asin}. f64 math identical
// to the previous per-thread finalize.
__device__ __forceinline__ void finalize_batch(const float* __restrict__ partB,
                                               float* __restrict__ scalOut) {
    __threadfence();                           // acquire other blocks' partials
    const int lane = threadIdx.x & 63;
    float v0 = 0.f, v1 = 0.f, v2 = 0.f, v3 = 0.f, v4 = 0.f, v5 = 0.f;
    #pragma unroll
    for (int s = 0; s < 4; s++) {
        const float* P = partB + (size_t)(lane + 64 * s) * 8;
        const float4 a = *(const float4*)P;
        const float4 c = *(const float4*)(P + 4);
        v0 += a.x; v1 += a.y; v2 += a.z; v3 += a.w; v4 += c.x; v5 += c.y;
    }
    #pragma unroll
    for (int m = 1; m < 64; m <<= 1) {
        v0 += __shfl_xor(v0, m, 64);
        v1 += __shfl_xor(v1, m, 64);
        v2 += __shfl_xor(v2, m, 64);
        v3 += __shfl_xor(v3, m, 64);
        v4 += __shfl_xor(v4, m, 64);
        v5 += __shfl_xor(v5, m, 64);
    }
    if (lane == 0) {
        const double sS  = (double)v0;
        const double inv = 1.0 / sS;
        const double cxd = (double)v1 * inv;
        const double cyd = (double)v2 * inv;
        float4 r;
        r.x = (float)cxd;
        r.y = (float)cyd;
        r.z = (float)((double)v3 * inv - cxd * cyd);   // cossin
        r.w = (float)((double)v4 * inv - cxd * cxd);   // bsin
        const float as_ = (float)((double)v5 * inv - cyd * cyd); // asin
        *(float4*)scalOut = r;
        scalOut[4] = as_;
    }
}

__device__ __forceinline__ void evalF(float uc, float ud, float ur, float qv,
                                      float dx, float dy,
                                      float cossin, float bsin, float asin_,
                                      float& a, float& bv, float& qn) {
    float Tx = -dx * cossin + dy * bsin;
    float Ty =  dy * cossin - dx * asin_;
    const float rn = __builtin_amdgcn_rsqf(Tx * Tx + Ty * Ty + 1e-20f);
    Tx *= rn; Ty *= rn;
    qn = qv - ((ud - uc) * Tx + (ur - uc) * Ty);
    a  = Tx * qn;
    bv = Ty * qn;
}

// u0 = sigmoid(o) (rounded to fp16); q0 = 0; o -> fp16; partials[0] from
// rounded u; last block per batch finalizes scalars[0].
__global__ __launch_bounds__(256) void init_kernel(const float* __restrict__ o,
                                                   h16* __restrict__ u,
                                                   h16* __restrict__ q,
                                                   h16* __restrict__ oh,
                                                   float* __restrict__ part0,
                                                   float* __restrict__ scal0,
                                                   unsigned* __restrict__ cnt0) {
    const int b     = blockIdx.x & 7;
    const int chunk = blockIdx.x >> 3;
    const int within = chunk * 1024 + threadIdx.x * 4;
    const int pix = b * NPIX + within;
    const int i = within >> 9;
    const int j = within & (WW - 1);
    const float4 ov = *(const float4*)(o + pix);

    half4v oh4; half4v uh4; half4v qz;
    float urf[4];
    const float uv[4] = {fast_sigmoid(ov.x), fast_sigmoid(ov.y),
                         fast_sigmoid(ov.z), fast_sigmoid(ov.w)};
    const float of[4] = {ov.x, ov.y, ov.z, ov.w};
    #pragma unroll
    for (int kk = 0; kk < 4; kk++) {
        oh4[kk] = (h16)of[kk];
        uh4[kk] = (h16)uv[kk];
        urf[kk] = (float)uh4[kk];
        qz[kk]  = (h16)0.f;
    }
    *(half4v*)(u + pix)  = uh4;
    *(half4v*)(q + pix)  = qz;
    *(half4v*)(oh + pix) = oh4;

    float s0 = 0.f, sy = 0.f, syy = 0.f;
    #pragma unroll
    for (int kk = 0; kk < 4; kk++) {
        const float y = (float)(j + 1 + kk);
        s0 += urf[kk]; sy += urf[kk] * y; syy += urf[kk] * y * y;
    }
    // per-wave x is uniform here (a wave covers 256 consecutive pixels of one row)
    if (tail_reduce6(s0, sy, syy, (float)(i + 1),
                     part0 + ((size_t)b * BLK_PER_BATCH + chunk) * 8, cnt0 + b)) {
        if (threadIdx.x < 64)
            finalize_batch(part0 + (size_t)b * BLK_PER_BATCH * 8, scal0 + b * 8);
    }
}

// One fused iteration, fp16 state. Batch scalars arrive precomputed (5 uniform
// floats) from the previous kernel's last-block finalize — no per-thread
// partials loads / butterfly / f64. evalF/sigmoid use 1-inst rsq/rcp/exp.
__global__ __launch_bounds__(256) void step_kernel(const h16* __restrict__ oh,
                                                   const h16* __restrict__ uA,
                                                   const h16* __restrict__ qA,
                                                   h16* __restrict__ uB,
                                                   h16* __restrict__ qB,
                                                   const float* __restrict__ scalIn,
                                                   float* __restrict__ partOut,
                                                   float* __restrict__ scalOut,
                                                   unsigned* __restrict__ cntOut,
                                                   float* __restrict__ out,
                                                   int lastFlag) {
    const int b    = blockIdx.x & 7;
    const int tile = blockIdx.x >> 3;
    const int j0 = (tile & 7) * TX;
    const int i0 = (tile >> 3) * TY;
    const h16* ubase = uA + (size_t)b * NPIX;
    const h16* qbase = qA + (size_t)b * NPIX;

    const int lin  = threadIdx.x;
    const int tx = lin & 15;
    const int ty = lin >> 4;
    const int i  = i0 + ty;
    const int jb = j0 + 4 * tx;
    const int loff = i * WW + jb;
    const size_t goff = (size_t)b * NPIX + loff;

    // ======== entry: batch scalars (uniform) + all global loads ========
    const float4 sc = *(const float4*)(scalIn + b * 8);
    const float asin_s = scalIn[b * 8 + 4];

    // u window: rows i-2..i+2, cols jb-2..jb+5, per row: half2 | half4 | half2
    const bool lok = (jb > 0);
    const bool rok = (jb + 4 < WW);
    half2v uL[5]; half4v uM[5]; half2v uR[5];
    #pragma unroll
    for (int r = 0; r < 5; r++) {
        const int ii = i - 2 + r;
        const bool rowok = (ii >= 0 && ii < HH);
        half2v l; l[0] = (h16)0.f; l[1] = (h16)0.f;
        half4v m; m[0] = (h16)0.f; m[1] = (h16)0.f; m[2] = (h16)0.f; m[3] = (h16)0.f;
        half2v rr; rr[0] = (h16)0.f; rr[1] = (h16)0.f;
        if (rowok) {
            const h16* rowp = ubase + ii * WW;
            m = *(const half4v*)(rowp + jb);
            if (lok) l  = *(const half2v*)(rowp + jb - 2);
            if (rok) rr = *(const half2v*)(rowp + jb + 4);
        }
        uL[r] = l; uM[r] = m; uR[r] = rr;
    }
    const half4v qc4h = *(const half4v*)(qbase + loff);
    const half4v qu4h = *(const half4v*)(qbase + ((i > 0) ? loff - WW : loff));
    const h16    qlh  = qbase[(jb > 0) ? loff - 1 : loff];
    const half4v o4h  = *(const half4v*)(oh + goff);

    const float cxf = sc.x, cyf = sc.y, cossin = sc.z, bsin = sc.w;

    // ======== rows 1..3 to fp32 (kept), rows 0/4 consumed in v-pass ========
    float U1[8], U2[8], U3[8], vs[8];
    {
        float r0[8], r4[8];
        #pragma unroll
        for (int c = 0; c < 2; c++) {
            r0[c]   = (float)uL[0][c]; U1[c]   = (float)uL[1][c]; U2[c]   = (float)uL[2][c];
            U3[c]   = (float)uL[3][c]; r4[c]   = (float)uL[4][c];
            r0[c+6] = (float)uR[0][c]; U1[c+6] = (float)uR[1][c]; U2[c+6] = (float)uR[2][c];
            U3[c+6] = (float)uR[3][c]; r4[c+6] = (float)uR[4][c];
        }
        #pragma unroll
        for (int c = 0; c < 4; c++) {
            r0[c+2] = (float)uM[0][c]; U1[c+2] = (float)uM[1][c]; U2[c+2] = (float)uM[2][c];
            U3[c+2] = (float)uM[3][c]; r4[c+2] = (float)uM[4][c];
        }
        #pragma unroll
        for (int c = 0; c < 8; c++)
            vs[c] = W0f * (r0[c] + r4[c]) + W1f * (U1[c] + U3[c]) + U2[c];
    }

    const float Ri = edge1d(i);
    float p4[4];
    #pragma unroll
    for (int k = 0; k < 4; k++) {
        const float convU = W0f * (vs[k] + vs[k + 4]) + W1f * (vs[k + 1] + vs[k + 3]) + vs[k + 2];
        p4[k] = INV_NORM * (Ri * edge1d(jb + k) - 2.0f * convU);
    }

    const float dx  = (float)(i + 1) - cxf;
    const float dxu = (float)i - cxf;
    const float qcv[4] = {(float)qc4h[0], (float)qc4h[1], (float)qc4h[2], (float)qc4h[3]};
    const float quv[4] = {(float)qu4h[0], (float)qu4h[1], (float)qu4h[2], (float)qu4h[3]};
    const float ov4[4] = {(float)o4h[0], (float)o4h[1], (float)o4h[2], (float)o4h[3]};
    const float qlv = (float)qlh;

    float a_c[4], b_c[4], qn[4], a_u[4];
    #pragma unroll
    for (int k = 0; k < 4; k++) {
        const float dy = (float)(jb + k + 1) - cyf;
        evalF(U2[k + 2], U3[k + 2], U2[k + 3], qcv[k],
              dx, dy, cossin, bsin, asin_s, a_c[k], b_c[k], qn[k]);
        float au, bu_d, qu_d;
        evalF(U1[k + 2], U2[k + 2], U1[k + 3], quv[k],
              dxu, dy, cossin, bsin, asin_s, au, bu_d, qu_d);
        a_u[k] = (i > 0) ? au : 0.f;
    }
    float b_l = 0.f;
    {
        float al_d, bl, ql_d;
        evalF(U2[1], U3[1], U2[2], qlv,
              dx, (float)jb - cyf, cossin, bsin, asin_s, al_d, bl, ql_d);
        b_l = (jb > 0) ? bl : 0.f;
    }

    float un4[4], t4[4];
    #pragma unroll
    for (int k = 0; k < 4; k++) {
        const float bleft = (k == 0) ? b_l : b_c[k - 1];
        const float Tq = a_c[k] + b_c[k] - a_u[k] - bleft;
        t4[k]  = ov4[k] - p4[k] - Tq;
        un4[k] = fast_sigmoid(t4[k]);
    }

    // round state to fp16; sums use the ROUNDED u for field consistency
    half4v uh4, qh4;
    float urf[4];
    #pragma unroll
    for (int k = 0; k < 4; k++) {
        uh4[k] = (h16)un4[k];
        urf[k] = (float)uh4[k];
        qh4[k] = (h16)qn[k];
    }
    *(half4v*)(uB + goff) = uh4;
    *(half4v*)(qB + goff) = qh4;
    if (lastFlag) {
        *(float4*)(out + goff) = make_float4(t4[0], t4[1], t4[2], t4[3]);
        return;  // no next iteration: skip partials/finalize entirely
    }

    float s0 = 0.f, sy = 0.f, syy = 0.f;
    #pragma unroll
    for (int k = 0; k < 4; k++) {
        const float y = (float)(jb + k + 1);
        s0 += urf[k]; sy += urf[k] * y; syy += urf[k] * y * y;
    }
    if (tail_reduce6(s0, sy, syy, (float)(i + 1),
                     partOut + ((size_t)b * BLK_PER_BATCH + tile) * 8, cntOut + b)) {
        if (threadIdx.x < 64)
            finalize_batch(partOut + (size_t)b * BLK_PER_BATCH * 8, scalOut + b * 8);
    }
}

extern "C" void kernel_launch(void* const* d_in, const int* in_sizes, int n_in,
                              void* d_out, int out_size, void* d_ws, size_t ws_size,
                              hipStream_t stream) {
    const float* o = (const float*)d_in[0];
    float* out = (float*)d_out;

    h16* uA = (h16*)d_ws;
    h16* uB = uA + (size_t)NTOT;
    h16* qA = uB + (size_t)NTOT;
    h16* qB = qA + (size_t)NTOT;
    h16* oh = qB + (size_t)NTOT;
    float* partials = (float*)(oh + (size_t)NTOT);                  // 51 * 16384 floats
    float* scalars  = partials + (size_t)(ITER + 1) * PART_ITER_STRIDE; // 51 * 64 floats
    unsigned* counters = (unsigned*)(scalars + (size_t)(ITER + 1) * SCAL_STRIDE); // 51 * 8

    // zero the per-iteration last-block counters (graph-capturable)
    hipMemsetAsync(counters, 0, (ITER + 1) * BB * sizeof(unsigned), stream);

    init_kernel<<<2048, 256, 0, stream>>>(o, uA, qA, oh, partials, scalars, counters);

    h16 *ua = uA, *ub = uB, *qa = qA, *qb = qB;
    for (int k = 0; k < ITER; k++) {
        step_kernel<<<2048, 256, 0, stream>>>(
            oh, ua, qa, ub, qb,
            scalars + (size_t)k * SCAL_STRIDE,
            partials + (size_t)(k + 1) * PART_ITER_STRIDE,
            scalars + (size_t)(k + 1) * SCAL_STRIDE,
            counters + (size_t)(k + 1) * BB,
            out, (k == ITER - 1) ? 1 : 0);
        h16* tmp;
        tmp = ua; ua = ub; ub = tmp;
        tmp = qa; qa = qb; qb = tmp;
    }
}

// Round 4
// 670.456 us; speedup vs baseline: 4.6422x; 4.6422x over previous
//
#include <hip/hip_runtime.h>
#include <math.h>

typedef _Float16 h16;
typedef h16 half4v __attribute__((ext_vector_type(4)));
typedef h16 half2v __attribute__((ext_vector_type(2)));

#define HH 512
#define WW 512
#define BB 8
#define NPIX (HH*WW)        // 262144
#define NTOT (BB*NPIX)      // 2097152
#define ITER 50

#define TX 64
#define TY 16

#define BLK_PER_BATCH 256
#define PART_ITER_STRIDE (BB*BLK_PER_BATCH*8)   // 16384 floats per iteration

// Gaussian 5x5 (sigma=5)
constexpr double W0d = 0.92311634638663587;  // exp(-0.08)
constexpr double W1d = 0.98019867330675525;  // exp(-0.02)
constexpr double SUM1D = 1.0 + 2.0*(W0d + W1d);
constexpr float  INV_NORM = (float)(1.0/(SUM1D*SUM1D + 1e-15));
constexpr float  W0f = (float)W0d;
constexpr float  W1f = (float)W1d;
constexpr float  S1f = (float)SUM1D;

// fast sigmoid: v_exp + v_rcp (1-2 ulp; fp16 state rounding dominates)
__device__ __forceinline__ float fast_sigmoid(float x) {
    const float e = __expf(-x);
    return __builtin_amdgcn_rcpf(1.0f + e);
}

__device__ __forceinline__ float edge1d(int v) {
    float r = S1f;
    if (v == 0 || v == HH - 1) r = S1f - W0f - W1f;
    else if (v == 1 || v == HH - 2) r = S1f - W0f;
    return r;
}

// Block-level reduce of 6 floats, one plain store to private partials slot.
// (round-0 verbatim: no atomics, no fences — each block owns its slot)
__device__ __forceinline__ void reduce6_store(float v[6], float* dst8) {
    #pragma unroll
    for (int kk = 0; kk < 6; kk++) {
        float x = v[kk];
        #pragma unroll
        for (int off = 32; off > 0; off >>= 1) x += __shfl_down(x, off, 64);
        v[kk] = x;
    }
    __shared__ float sm[4][6];
    const int lane = threadIdx.x & 63;
    const int wv   = threadIdx.x >> 6;
    if (lane == 0) {
        #pragma unroll
        for (int kk = 0; kk < 6; kk++) sm[wv][kk] = v[kk];
    }
    __syncthreads();
    if (threadIdx.x == 0) {
        float tt[6];
        #pragma unroll
        for (int kk = 0; kk < 6; kk++) tt[kk] = sm[0][kk] + sm[1][kk] + sm[2][kk] + sm[3][kk];
        *(float4*)dst8       = make_float4(tt[0], tt[1], tt[2], tt[3]);
        *(float4*)(dst8 + 4) = make_float4(tt[4], tt[5], 0.f, 0.f);
    }
}

__device__ __forceinline__ void evalF(float uc, float ud, float ur, float qv,
                                      float dx, float dy,
                                      float cossin, float bsin, float asin_,
                                      float& a, float& bv, float& qn) {
    float Tx = -dx * cossin + dy * bsin;
    float Ty =  dy * cossin - dx * asin_;
    const float rn = __builtin_amdgcn_rsqf(Tx * Tx + Ty * Ty + 1e-20f);
    Tx *= rn; Ty *= rn;
    qn = qv - ((ud - uc) * Tx + (ur - uc) * Ty);
    a  = Tx * qn;
    bv = Ty * qn;
}

// u0 = sigmoid(o) (rounded to fp16); q0 = 0; o -> fp16; partials[0] from rounded u.
__global__ __launch_bounds__(256) void init_kernel(const float* __restrict__ o,
                                                   h16* __restrict__ u,
                                                   h16* __restrict__ q,
                                                   h16* __restrict__ oh,
                                                   float* __restrict__ part0) {
    const int b     = blockIdx.x & 7;
    const int chunk = blockIdx.x >> 3;
    const int within = chunk * 1024 + threadIdx.x * 4;
    const int pix = b * NPIX + within;
    const int i = within >> 9;
    const int j = within & (WW - 1);
    float4 ov = *(const float4*)(o + pix);

    half4v oh4; half4v uh4; half4v qz;
    float urf[4];
    const float uv[4] = {fast_sigmoid(ov.x), fast_sigmoid(ov.y),
                         fast_sigmoid(ov.z), fast_sigmoid(ov.w)};
    const float of[4] = {ov.x, ov.y, ov.z, ov.w};
    #pragma unroll
    for (int kk = 0; kk < 4; kk++) {
        oh4[kk] = (h16)of[kk];
        uh4[kk] = (h16)uv[kk];
        urf[kk] = (float)uh4[kk];
        qz[kk]  = (h16)0.f;
    }
    *(half4v*)(u + pix)  = uh4;
    *(half4v*)(q + pix)  = qz;
    *(half4v*)(oh + pix) = oh4;

    const float x = (float)(i + 1);
    float v[6] = {0.f, 0.f, 0.f, 0.f, 0.f, 0.f};
    #pragma unroll
    for (int kk = 0; kk < 4; kk++) {
        const float uu = urf[kk];
        const float y  = (float)(j + 1 + kk);
        v[0] += uu; v[1] += uu * x; v[2] += uu * y;
        v[3] += uu * x * y; v[4] += uu * x * x; v[5] += uu * y * y;
    }
    reduce6_store(v, part0 + ((size_t)b * BLK_PER_BATCH + chunk) * 8);
}

// One fused iteration, fp16 state, round-0 structure (per-thread partials
// finalize — no atomics/fences), with fast rsq/rcp/exp intrinsics and a
// register-dieted u-window (rows 0/4 consumed on the fly).
__global__ __launch_bounds__(256) void step_kernel(const h16* __restrict__ oh,
                                                   const h16* __restrict__ uA,
                                                   const h16* __restrict__ qA,
                                                   h16* __restrict__ uB,
                                                   h16* __restrict__ qB,
                                                   const float* __restrict__ partIn,
                                                   float* __restrict__ partOut,
                                                   float* __restrict__ out,
                                                   int lastFlag) {
    const int b    = blockIdx.x & 7;
    const int tile = blockIdx.x >> 3;
    const int j0 = (tile & 7) * TX;
    const int i0 = (tile >> 3) * TY;
    const h16* ubase = uA + (size_t)b * NPIX;
    const h16* qbase = qA + (size_t)b * NPIX;

    const int lin  = threadIdx.x;
    const int lane = lin & 63;
    const int tx = lin & 15;
    const int ty = lin >> 4;
    const int i  = i0 + ty;
    const int jb = j0 + 4 * tx;
    const int loff = i * WW + jb;
    const size_t goff = (size_t)b * NPIX + loff;

    // ======== entry: issue ALL global loads ========
    // partials: each wave covers all 256 slots of this batch
    float4 pA[4], pB[4];
    #pragma unroll
    for (int s = 0; s < 4; s++) {
        const float* P = partIn + (size_t)b * (BLK_PER_BATCH * 8) + (lane + 64 * s) * 8;
        pA[s] = *(const float4*)P;
        pB[s] = *(const float4*)(P + 4);
    }
    // u window: rows i-2..i+2, cols jb-2..jb+5, per row: half2 | half4 | half2
    const bool lok = (jb > 0);
    const bool rok = (jb + 4 < WW);
    half2v uL[5]; half4v uM[5]; half2v uR[5];
    #pragma unroll
    for (int r = 0; r < 5; r++) {
        const int ii = i - 2 + r;
        const bool rowok = (ii >= 0 && ii < HH);
        half2v l; l[0] = (h16)0.f; l[1] = (h16)0.f;
        half4v m; m[0] = (h16)0.f; m[1] = (h16)0.f; m[2] = (h16)0.f; m[3] = (h16)0.f;
        half2v rr; rr[0] = (h16)0.f; rr[1] = (h16)0.f;
        if (rowok) {
            const h16* rowp = ubase + ii * WW;
            m = *(const half4v*)(rowp + jb);
            if (lok) l  = *(const half2v*)(rowp + jb - 2);
            if (rok) rr = *(const half2v*)(rowp + jb + 4);
        }
        uL[r] = l; uM[r] = m; uR[r] = rr;
    }
    // q / o (clamped addresses)
    const half4v qc4h = *(const half4v*)(qbase + loff);
    const half4v qu4h = *(const half4v*)(qbase + ((i > 0) ? loff - WW : loff));
    const h16    qlh  = qbase[(jb > 0) ? loff - 1 : loff];
    const half4v o4h  = *(const half4v*)(oh + goff);

    // ======== per-wave scalar finalize (butterfly, no LDS / no barrier) ========
    float v6[6] = {0.f, 0.f, 0.f, 0.f, 0.f, 0.f};
    #pragma unroll
    for (int s = 0; s < 4; s++) {
        v6[0] += pA[s].x; v6[1] += pA[s].y; v6[2] += pA[s].z;
        v6[3] += pA[s].w; v6[4] += pB[s].x; v6[5] += pB[s].y;
    }
    #pragma unroll
    for (int mask = 1; mask < 64; mask <<= 1) {
        #pragma unroll
        for (int c = 0; c < 6; c++) v6[c] += __shfl_xor(v6[c], mask, 64);
    }
    const double sS  = (double)v6[0];
    const double inv = 1.0 / sS;
    const double cxd = (double)v6[1] * inv;
    const double cyd = (double)v6[2] * inv;
    const float cxf    = (float)cxd;
    const float cyf    = (float)cyd;
    const float cossin = (float)((double)v6[3] * inv - cxd * cyd);
    const float bsin   = (float)((double)v6[4] * inv - cxd * cxd);
    const float asin_  = (float)((double)v6[5] * inv - cyd * cyd);

    // ======== rows 1..3 to fp32 (kept), rows 0/4 consumed in v-pass ========
    float U1[8], U2[8], U3[8], vs[8];
    {
        float r0[8], r4[8];
        #pragma unroll
        for (int c = 0; c < 2; c++) {
            r0[c]   = (float)uL[0][c]; U1[c]   = (float)uL[1][c]; U2[c]   = (float)uL[2][c];
            U3[c]   = (float)uL[3][c]; r4[c]   = (float)uL[4][c];
            r0[c+6] = (float)uR[0][c]; U1[c+6] = (float)uR[1][c]; U2[c+6] = (float)uR[2][c];
            U3[c+6] = (float)uR[3][c]; r4[c+6] = (float)uR[4][c];
        }
        #pragma unroll
        for (int c = 0; c < 4; c++) {
            r0[c+2] = (float)uM[0][c]; U1[c+2] = (float)uM[1][c]; U2[c+2] = (float)uM[2][c];
            U3[c+2] = (float)uM[3][c]; r4[c+2] = (float)uM[4][c];
        }
        #pragma unroll
        for (int c = 0; c < 8; c++)
            vs[c] = W0f * (r0[c] + r4[c]) + W1f * (U1[c] + U3[c]) + U2[c];
    }

    const float Ri = edge1d(i);
    float p4[4];
    #pragma unroll
    for (int k = 0; k < 4; k++) {
        const float convU = W0f * (vs[k] + vs[k + 4]) + W1f * (vs[k + 1] + vs[k + 3]) + vs[k + 2];
        p4[k] = INV_NORM * (Ri * edge1d(jb + k) - 2.0f * convU);
    }

    const float dx  = (float)(i + 1) - cxf;
    const float dxu = (float)i - cxf;
    const float qcv[4] = {(float)qc4h[0], (float)qc4h[1], (float)qc4h[2], (float)qc4h[3]};
    const float quv[4] = {(float)qu4h[0], (float)qu4h[1], (float)qu4h[2], (float)qu4h[3]};
    const float ov4[4] = {(float)o4h[0], (float)o4h[1], (float)o4h[2], (float)o4h[3]};
    const float qlv = (float)qlh;

    float a_c[4], b_c[4], qn[4], a_u[4];
    #pragma unroll
    for (int k = 0; k < 4; k++) {
        const float dy = (float)(jb + k + 1) - cyf;
        evalF(U2[k + 2], U3[k + 2], U2[k + 3], qcv[k],
              dx, dy, cossin, bsin, asin_, a_c[k], b_c[k], qn[k]);
        float au, bu_d, qu_d;
        evalF(U1[k + 2], U2[k + 2], U1[k + 3], quv[k],
              dxu, dy, cossin, bsin, asin_, au, bu_d, qu_d);
        a_u[k] = (i > 0) ? au : 0.f;
    }
    float b_l = 0.f;
    {
        float al_d, bl, ql_d;
        evalF(U2[1], U3[1], U2[2], qlv,
              dx, (float)jb - cyf, cossin, bsin, asin_, al_d, bl, ql_d);
        b_l = (jb > 0) ? bl : 0.f;
    }

    float un4[4], t4[4];
    #pragma unroll
    for (int k = 0; k < 4; k++) {
        const float bleft = (k == 0) ? b_l : b_c[k - 1];
        const float Tq = a_c[k] + b_c[k] - a_u[k] - bleft;
        t4[k]  = ov4[k] - p4[k] - Tq;
        un4[k] = fast_sigmoid(t4[k]);
    }

    // round state to fp16; sums use the ROUNDED u for field consistency
    half4v uh4, qh4;
    float urf[4];
    #pragma unroll
    for (int k = 0; k < 4; k++) {
        uh4[k] = (h16)un4[k];
        urf[k] = (float)uh4[k];
        qh4[k] = (h16)qn[k];
    }
    *(half4v*)(uB + goff) = uh4;
    *(half4v*)(qB + goff) = qh4;
    if (lastFlag) {
        *(float4*)(out + goff) = make_float4(t4[0], t4[1], t4[2], t4[3]);
        return;  // no next iteration: partials not needed
    }

    const float x = (float)(i + 1);
    float s0 = 0.f, sy = 0.f, syy = 0.f;
    #pragma unroll
    for (int k = 0; k < 4; k++) {
        const float y = (float)(jb + k + 1);
        s0 += urf[k]; sy += urf[k] * y; syy += urf[k] * y * y;
    }
    float v[6] = {s0, x * s0, sy, x * sy, x * x * s0, syy};
    reduce6_store(v, partOut + ((size_t)b * BLK_PER_BATCH + tile) * 8);
}

extern "C" void kernel_launch(void* const* d_in, const int* in_sizes, int n_in,
                              void* d_out, int out_size, void* d_ws, size_t ws_size,
                              hipStream_t stream) {
    const float* o = (const float*)d_in[0];
    float* out = (float*)d_out;

    h16* uA = (h16*)d_ws;
    h16* uB = uA + (size_t)NTOT;
    h16* qA = uB + (size_t)NTOT;
    h16* qB = qA + (size_t)NTOT;
    h16* oh = qB + (size_t)NTOT;
    float* partials = (float*)(oh + (size_t)NTOT);   // 51 iters * 16384 floats

    init_kernel<<<2048, 256, 0, stream>>>(o, uA, qA, oh, partials);

    h16 *ua = uA, *ub = uB, *qa = qA, *qb = qB;
    for (int k = 0; k < ITER; k++) {
        step_kernel<<<2048, 256, 0, stream>>>(
            oh, ua, qa, ub, qb,
            partials + (size_t)k * PART_ITER_STRIDE,
            partials + (size_t)(k + 1) * PART_ITER_STRIDE,
            out, (k == ITER - 1) ? 1 : 0);
        h16* tmp;
        tmp = ua; ua = ub; ub = tmp;
        tmp = qa; qa = qb; qb = tmp;
    }
}

// Round 6
// 545.475 us; speedup vs baseline: 5.7059x; 1.2291x over previous
//
#include <hip/hip_runtime.h>
#include <math.h>

typedef _Float16 h16;
typedef h16 half8v __attribute__((ext_vector_type(8)));
typedef h16 half4v __attribute__((ext_vector_type(4)));
typedef h16 half2v __attribute__((ext_vector_type(2)));

#define HH 512
#define WW 512
#define BB 8
#define NPIX (HH*WW)        // 262144
#define NTOT (BB*NPIX)      // 2097152
#define ITER 50

#define TX 64               // tile cols
#define TILE_ROWS 32        // tile rows = 16 ty * 2 rows/thread

#define BLK_PER_BATCH 128
#define PART_ITER_STRIDE (BB*BLK_PER_BATCH*8)   // 8192 floats per iteration

// Gaussian 5x5 (sigma=5)
constexpr double W0d = 0.92311634638663587;  // exp(-0.08)
constexpr double W1d = 0.98019867330675525;  // exp(-0.02)
constexpr double SUM1D = 1.0 + 2.0*(W0d + W1d);
constexpr float  INV_NORM = (float)(1.0/(SUM1D*SUM1D + 1e-15));
constexpr float  W0f = (float)W0d;
constexpr float  W1f = (float)W1d;
constexpr float  S1f = (float)SUM1D;

// fast sigmoid: v_exp + v_rcp (1-2 ulp; fp16 state rounding dominates)
__device__ __forceinline__ float fast_sigmoid(float x) {
    const float e = __expf(-x);
    return __builtin_amdgcn_rcpf(1.0f + e);
}

__device__ __forceinline__ float edge1d(int v) {
    float r = S1f;
    if (v == 0 || v == HH - 1) r = S1f - W0f - W1f;
    else if (v == 1 || v == HH - 2) r = S1f - W0f;
    return r;
}

// Block-level reduce of 6 floats, one plain store to private partials slot.
// (no atomics, no fences — each block owns its slot)
__device__ __forceinline__ void reduce6_store(float v[6], float* dst8) {
    #pragma unroll
    for (int kk = 0; kk < 6; kk++) {
        float x = v[kk];
        #pragma unroll
        for (int off = 32; off > 0; off >>= 1) x += __shfl_down(x, off, 64);
        v[kk] = x;
    }
    __shared__ float sm[4][6];
    const int lane = threadIdx.x & 63;
    const int wv   = threadIdx.x >> 6;
    if (lane == 0) {
        #pragma unroll
        for (int kk = 0; kk < 6; kk++) sm[wv][kk] = v[kk];
    }
    __syncthreads();
    if (threadIdx.x == 0) {
        float tt[6];
        #pragma unroll
        for (int kk = 0; kk < 6; kk++) tt[kk] = sm[0][kk] + sm[1][kk] + sm[2][kk] + sm[3][kk];
        *(float4*)dst8       = make_float4(tt[0], tt[1], tt[2], tt[3]);
        *(float4*)(dst8 + 4) = make_float4(tt[4], tt[5], 0.f, 0.f);
    }
}

__device__ __forceinline__ void evalF(float uc, float ud, float ur, float qv,
                                      float dx, float dy,
                                      float cossin, float bsin, float asin_,
                                      float& a, float& bv, float& qn) {
    float Tx = -dx * cossin + dy * bsin;
    float Ty =  dy * cossin - dx * asin_;
    const float rn = __builtin_amdgcn_rsqf(Tx * Tx + Ty * Ty + 1e-20f);
    Tx *= rn; Ty *= rn;
    qn = qv - ((ud - uc) * Tx + (ur - uc) * Ty);
    a  = Tx * qn;
    bv = Ty * qn;
}

// u0 = sigmoid(o) (rounded to fp16); q0 = 0; o -> fp16; partials[0] from rounded u.
// 1024 blocks x 256 threads x 8 px.
__global__ __launch_bounds__(256) void init_kernel(const float* __restrict__ o,
                                                   h16* __restrict__ u,
                                                   h16* __restrict__ q,
                                                   h16* __restrict__ oh,
                                                   float* __restrict__ part0) {
    const int b     = blockIdx.x & 7;
    const int chunk = blockIdx.x >> 3;                 // 0..127
    const int within = chunk * 2048 + threadIdx.x * 8; // 8 consecutive px, row-aligned
    const int pix = b * NPIX + within;
    const int i = within >> 9;
    const int j = within & (WW - 1);
    const float4 ov0 = *(const float4*)(o + pix);
    const float4 ov1 = *(const float4*)(o + pix + 4);

    const float of[8] = {ov0.x, ov0.y, ov0.z, ov0.w, ov1.x, ov1.y, ov1.z, ov1.w};
    half8v oh8, uh8, qz;
    float urf[8];
    #pragma unroll
    for (int kk = 0; kk < 8; kk++) {
        oh8[kk] = (h16)of[kk];
        uh8[kk] = (h16)fast_sigmoid(of[kk]);
        urf[kk] = (float)uh8[kk];
        qz[kk]  = (h16)0.f;
    }
    *(half8v*)(u + pix)  = uh8;
    *(half8v*)(q + pix)  = qz;
    *(half8v*)(oh + pix) = oh8;

    const float x = (float)(i + 1);
    float s0 = 0.f, sy = 0.f, syy = 0.f;
    #pragma unroll
    for (int kk = 0; kk < 8; kk++) {
        const float y = (float)(j + 1 + kk);
        s0 += urf[kk]; sy += urf[kk] * y; syy += urf[kk] * y * y;
    }
    float v[6] = {s0, x * s0, sy, x * sy, x * x * s0, syy};
    reduce6_store(v, part0 + ((size_t)b * BLK_PER_BATCH + chunk) * 8);
}

// One fused iteration, fp16 state. Each thread computes a 2x4 pixel block:
// rows (ia, ia+1) x cols (jb..jb+3). Bit-identical math to the 1-row version:
// row B's "up" divergence term is row A's center eval (same formula+inputs).
// u window: 6 rows x 8 cols for 8 outputs (12 B/px vs 20 B/px before).
__global__ __launch_bounds__(256) void step_kernel(const h16* __restrict__ oh,
                                                   const h16* __restrict__ uA,
                                                   const h16* __restrict__ qA,
                                                   h16* __restrict__ uB,
                                                   h16* __restrict__ qB,
                                                   const float* __restrict__ partIn,
                                                   float* __restrict__ partOut,
                                                   float* __restrict__ out,
                                                   int lastFlag) {
    const int b    = blockIdx.x & 7;
    const int tile = blockIdx.x >> 3;          // 0..127
    const int j0 = (tile & 7) * TX;
    const int i0 = (tile >> 3) * TILE_ROWS;    // 0..480 step 32
    const h16* ubase = uA + (size_t)b * NPIX;
    const h16* qbase = qA + (size_t)b * NPIX;

    const int lin  = threadIdx.x;
    const int lane = lin & 63;
    const int tx = lin & 15;
    const int ty = lin >> 4;
    const int ia = i0 + 2 * ty;                // row A (0..510 even)
    const int jb = j0 + 4 * tx;
    const int loffA = ia * WW + jb;
    const int loffB = loffA + WW;
    const size_t goffA = (size_t)b * NPIX + loffA;
    const size_t goffB = goffA + WW;

    // ======== entry: issue ALL global loads ========
    // partials: 128 slots/batch, each lane covers slots {lane, lane+64}
    const float* P0 = partIn + (size_t)b * (BLK_PER_BATCH * 8) + lane * 8;
    const float4 pA0 = *(const float4*)P0;
    const float4 pB0 = *(const float4*)(P0 + 4);
    const float4 pA1 = *(const float4*)(P0 + 64 * 8);
    const float4 pB1 = *(const float4*)(P0 + 64 * 8 + 4);

    // u window: rows ia-2..ia+3, cols jb-2..jb+5, per row: half2 | half4 | half2
    const bool lok = (jb > 0);
    const bool rok = (jb + 4 < WW);
    half2v uL[6]; half4v uM[6]; half2v uR[6];
    #pragma unroll
    for (int r = 0; r < 6; r++) {
        const int ii = ia - 2 + r;
        const bool rowok = (ii >= 0 && ii < HH);
        half2v l; l[0] = (h16)0.f; l[1] = (h16)0.f;
        half4v m; m[0] = (h16)0.f; m[1] = (h16)0.f; m[2] = (h16)0.f; m[3] = (h16)0.f;
        half2v rr; rr[0] = (h16)0.f; rr[1] = (h16)0.f;
        if (rowok) {
            const h16* rowp = ubase + ii * WW;
            m = *(const half4v*)(rowp + jb);
            if (lok) l  = *(const half2v*)(rowp + jb - 2);
            if (rok) rr = *(const half2v*)(rowp + jb + 4);
        }
        uL[r] = l; uM[r] = m; uR[r] = rr;
    }
    // q rows A, B, up(A-1); q-left scalars; o rows A, B
    const half4v qcAh = *(const half4v*)(qbase + loffA);
    const half4v qcBh = *(const half4v*)(qbase + loffB);
    const half4v quh  = *(const half4v*)(qbase + ((ia > 0) ? loffA - WW : loffA));
    const h16    qlAh = qbase[lok ? loffA - 1 : loffA];
    const h16    qlBh = qbase[lok ? loffB - 1 : loffB];
    const half4v oAh  = *(const half4v*)(oh + goffA);
    const half4v oBh  = *(const half4v*)(oh + goffB);

    // ======== per-wave scalar finalize (butterfly, no LDS / no barrier) ========
    float v6[6];
    v6[0] = pA0.x + pA1.x; v6[1] = pA0.y + pA1.y; v6[2] = pA0.z + pA1.z;
    v6[3] = pA0.w + pA1.w; v6[4] = pB0.x + pB1.x; v6[5] = pB0.y + pB1.y;
    #pragma unroll
    for (int mask = 1; mask < 64; mask <<= 1) {
        #pragma unroll
        for (int c = 0; c < 6; c++) v6[c] += __shfl_xor(v6[c], mask, 64);
    }
    const double sS  = (double)v6[0];
    const double inv = 1.0 / sS;
    const double cxd = (double)v6[1] * inv;
    const double cyd = (double)v6[2] * inv;
    const float cxf    = (float)cxd;
    const float cyf    = (float)cyd;
    const float cossin = (float)((double)v6[3] * inv - cxd * cyd);
    const float bsin   = (float)((double)v6[4] * inv - cxd * cxd);
    const float asin_  = (float)((double)v6[5] * inv - cyd * cyd);

    // ======== streaming v-pass over 6 window rows; keep rows 1..4 cols 1..6 ========
    // vsA: vertical sums for output row A (window rows 0..4, w = W0,W1,1,W1,W0)
    // vsB: vertical sums for output row B (window rows 1..5)
    float vsA[8], vsB[8];
    float Ue[4][6];            // window rows 1..4, cols 1..6 (for evalF)
    constexpr float wAr[6] = {W0f, W1f, 1.f, W1f, W0f, 0.f};
    constexpr float wBr[6] = {0.f, W0f, W1f, 1.f, W1f, W0f};
    #pragma unroll
    for (int r = 0; r < 6; r++) {
        float U[8];
        U[0] = (float)uL[r][0]; U[1] = (float)uL[r][1];
        U[2] = (float)uM[r][0]; U[3] = (float)uM[r][1];
        U[4] = (float)uM[r][2]; U[5] = (float)uM[r][3];
        U[6] = (float)uR[r][0]; U[7] = (float)uR[r][1];
        #pragma unroll
        for (int c = 0; c < 8; c++) {
            if (r == 0)            vsA[c] = wAr[0] * U[c];
            else if (wAr[r] != 0.f) vsA[c] += wAr[r] * U[c];
            if (r == 1)            vsB[c] = wBr[1] * U[c];
            else if (wBr[r] != 0.f) vsB[c] += wBr[r] * U[c];
        }
        if (r >= 1 && r <= 4) {
            #pragma unroll
            for (int c = 0; c < 6; c++) Ue[r - 1][c] = U[c + 1];
        }
    }

    // ======== h-pass (conv complete) ========
    const float RiA = edge1d(ia);
    const float RiB = edge1d(ia + 1);
    float p4A[4], p4B[4];
    #pragma unroll
    for (int k = 0; k < 4; k++) {
        const float Rj = edge1d(jb + k);
        const float cA = W0f * (vsA[k] + vsA[k + 4]) + W1f * (vsA[k + 1] + vsA[k + 3]) + vsA[k + 2];
        const float cB = W0f * (vsB[k] + vsB[k + 4]) + W1f * (vsB[k + 1] + vsB[k + 3]) + vsB[k + 2];
        p4A[k] = INV_NORM * (RiA * Rj - 2.0f * cA);
        p4B[k] = INV_NORM * (RiB * Rj - 2.0f * cB);
    }

    const float dxA = (float)(ia + 1) - cxf;
    const float dxB = (float)(ia + 2) - cxf;
    const float dxu = (float)ia - cxf;
    const float qcA[4] = {(float)qcAh[0], (float)qcAh[1], (float)qcAh[2], (float)qcAh[3]};
    const float qcB[4] = {(float)qcBh[0], (float)qcBh[1], (float)qcBh[2], (float)qcBh[3]};
    const float quv[4] = {(float)quh[0], (float)quh[1], (float)quh[2], (float)quh[3]};

    // evals: row A center (also serves as row B's up), row A up, row B center
    float aA[4], bA[4], qnA[4], aUA[4], aB[4], bB[4], qnB[4];
    #pragma unroll
    for (int k = 0; k < 4; k++) {
        const float dy = (float)(jb + k + 1) - cyf;
        evalF(Ue[1][k + 1], Ue[2][k + 1], Ue[1][k + 2], qcA[k],
              dxA, dy, cossin, bsin, asin_, aA[k], bA[k], qnA[k]);
        float au, bu_d, qu_d;
        evalF(Ue[0][k + 1], Ue[1][k + 1], Ue[0][k + 2], quv[k],
              dxu, dy, cossin, bsin, asin_, au, bu_d, qu_d);
        aUA[k] = (ia > 0) ? au : 0.f;
        evalF(Ue[2][k + 1], Ue[3][k + 1], Ue[2][k + 2], qcB[k],
              dxB, dy, cossin, bsin, asin_, aB[k], bB[k], qnB[k]);
    }
    // left-boundary evals (col jb-1) for both rows
    float blA = 0.f, blB = 0.f;
    {
        const float dyl = (float)jb - cyf;
        float ad, bl, qd;
        evalF(Ue[1][0], Ue[2][0], Ue[1][1], (float)qlAh,
              dxA, dyl, cossin, bsin, asin_, ad, bl, qd);
        if (lok) blA = bl;
        evalF(Ue[2][0], Ue[3][0], Ue[2][1], (float)qlBh,
              dxB, dyl, cossin, bsin, asin_, ad, bl, qd);
        if (lok) blB = bl;
    }

    float t4A[4], t4B[4], unA[4], unB[4];
    #pragma unroll
    for (int k = 0; k < 4; k++) {
        const float blA_ = (k == 0) ? blA : bA[k - 1];
        const float blB_ = (k == 0) ? blB : bB[k - 1];
        const float TqA = aA[k] + bA[k] - aUA[k] - blA_;
        const float TqB = aB[k] + bB[k] - aA[k] - blB_;   // row B up = row A center
        t4A[k] = (float)oAh[k] - p4A[k] - TqA;
        t4B[k] = (float)oBh[k] - p4B[k] - TqB;
        unA[k] = fast_sigmoid(t4A[k]);
        unB[k] = fast_sigmoid(t4B[k]);
    }

    // round state to fp16; sums use the ROUNDED u for field consistency
    half4v uhA, uhB, qhA, qhB;
    float urA[4], urB[4];
    #pragma unroll
    for (int k = 0; k < 4; k++) {
        uhA[k] = (h16)unA[k]; urA[k] = (float)uhA[k]; qhA[k] = (h16)qnA[k];
        uhB[k] = (h16)unB[k]; urB[k] = (float)uhB[k]; qhB[k] = (h16)qnB[k];
    }
    *(half4v*)(uB + goffA) = uhA;
    *(half4v*)(uB + goffB) = uhB;
    *(half4v*)(qB + goffA) = qhA;
    *(half4v*)(qB + goffB) = qhB;
    if (lastFlag) {
        *(float4*)(out + goffA) = make_float4(t4A[0], t4A[1], t4A[2], t4A[3]);
        *(float4*)(out + goffB) = make_float4(t4B[0], t4B[1], t4B[2], t4B[3]);
        return;  // no next iteration: partials not needed
    }

    const float xA = (float)(ia + 1);
    const float xB = (float)(ia + 2);
    float s0A = 0.f, syA = 0.f, syyA = 0.f, s0B = 0.f, syB = 0.f, syyB = 0.f;
    #pragma unroll
    for (int k = 0; k < 4; k++) {
        const float y = (float)(jb + k + 1);
        s0A += urA[k]; syA += urA[k] * y; syyA += urA[k] * y * y;
        s0B += urB[k]; syB += urB[k] * y; syyB += urB[k] * y * y;
    }
    float v[6] = {s0A + s0B, xA * s0A + xB * s0B, syA + syB,
                  xA * syA + xB * syB, xA * xA * s0A + xB * xB * s0B, syyA + syyB};
    reduce6_store(v, partOut + ((size_t)b * BLK_PER_BATCH + tile) * 8);
}

extern "C" void kernel_launch(void* const* d_in, const int* in_sizes, int n_in,
                              void* d_out, int out_size, void* d_ws, size_t ws_size,
                              hipStream_t stream) {
    const float* o = (const float*)d_in[0];
    float* out = (float*)d_out;

    h16* uA = (h16*)d_ws;
    h16* uB = uA + (size_t)NTOT;
    h16* qA = uB + (size_t)NTOT;
    h16* qB = qA + (size_t)NTOT;
    h16* oh = qB + (size_t)NTOT;
    float* partials = (float*)(oh + (size_t)NTOT);   // 51 iters * 8192 floats

    init_kernel<<<1024, 256, 0, stream>>>(o, uA, qA, oh, partials);

    h16 *ua = uA, *ub = uB, *qa = qA, *qb = qB;
    for (int k = 0; k < ITER; k++) {
        step_kernel<<<1024, 256, 0, stream>>>(
            oh, ua, qa, ub, qb,
            partials + (size_t)k * PART_ITER_STRIDE,
            partials + (size_t)(k + 1) * PART_ITER_STRIDE,
            out, (k == ITER - 1) ? 1 : 0);
        h16* tmp;
        tmp = ua; ua = ub; ub = tmp;
        tmp = qa; qa = qb; qb = tmp;
    }
}

// Round 7
// 522.923 us; speedup vs baseline: 5.9519x; 1.0431x over previous
//
#include <hip/hip_runtime.h>
#include <math.h>

typedef _Float16 h16;
typedef h16 half8v __attribute__((ext_vector_type(8)));
typedef h16 half4v __attribute__((ext_vector_type(4)));
typedef h16 half2v __attribute__((ext_vector_type(2)));

#define HH 512
#define WW 512
#define BB 8
#define NPIX (HH*WW)        // 262144
#define NTOT (BB*NPIX)      // 2097152
#define ITER 50

#define TX 64               // tile cols
#define TILE_ROWS 64        // tile rows = 32 ty * 2 rows/thread

#define BLK_PER_BATCH 64
#define PART_ITER_STRIDE (BB*BLK_PER_BATCH*8)   // 4096 floats per iteration

// Gaussian 5x5 (sigma=5)
constexpr double W0d = 0.92311634638663587;  // exp(-0.08)
constexpr double W1d = 0.98019867330675525;  // exp(-0.02)
constexpr double SUM1D = 1.0 + 2.0*(W0d + W1d);
constexpr float  INV_NORM = (float)(1.0/(SUM1D*SUM1D + 1e-15));
constexpr float  W0f = (float)W0d;
constexpr float  W1f = (float)W1d;
constexpr float  S1f = (float)SUM1D;

// fast sigmoid: v_exp + v_rcp (1-2 ulp; fp16 state rounding dominates)
__device__ __forceinline__ float fast_sigmoid(float x) {
    const float e = __expf(-x);
    return __builtin_amdgcn_rcpf(1.0f + e);
}

__device__ __forceinline__ float edge1d(int v) {
    float r = S1f;
    if (v == 0 || v == HH - 1) r = S1f - W0f - W1f;
    else if (v == 1 || v == HH - 2) r = S1f - W0f;
    return r;
}

// Block-level reduce of 6 floats, one plain store to private partials slot.
// (no atomics, no fences — each block owns its slot)
__device__ __forceinline__ void reduce6_store(float v[6], float* dst8) {
    #pragma unroll
    for (int kk = 0; kk < 6; kk++) {
        float x = v[kk];
        #pragma unroll
        for (int off = 32; off > 0; off >>= 1) x += __shfl_down(x, off, 64);
        v[kk] = x;
    }
    __shared__ float sm[4][6];
    const int lane = threadIdx.x & 63;
    const int wv   = threadIdx.x >> 6;
    if (lane == 0) {
        #pragma unroll
        for (int kk = 0; kk < 6; kk++) sm[wv][kk] = v[kk];
    }
    __syncthreads();
    if (threadIdx.x == 0) {
        float tt[6];
        #pragma unroll
        for (int kk = 0; kk < 6; kk++) tt[kk] = sm[0][kk] + sm[1][kk] + sm[2][kk] + sm[3][kk];
        *(float4*)dst8       = make_float4(tt[0], tt[1], tt[2], tt[3]);
        *(float4*)(dst8 + 4) = make_float4(tt[4], tt[5], 0.f, 0.f);
    }
}

__device__ __forceinline__ void evalF(float uc, float ud, float ur, float qv,
                                      float dx, float dy,
                                      float cossin, float bsin, float asin_,
                                      float& a, float& bv, float& qn) {
    float Tx = -dx * cossin + dy * bsin;
    float Ty =  dy * cossin - dx * asin_;
    const float rn = __builtin_amdgcn_rsqf(Tx * Tx + Ty * Ty + 1e-20f);
    Tx *= rn; Ty *= rn;
    qn = qv - ((ud - uc) * Tx + (ur - uc) * Ty);
    a  = Tx * qn;
    bv = Ty * qn;
}

// u0 = sigmoid(o) (rounded to fp16); q0 = 0; o -> fp16; partials[0] from rounded u.
// 512 blocks x 256 threads x 16 px (one row segment per thread).
__global__ __launch_bounds__(256) void init_kernel(const float* __restrict__ o,
                                                   h16* __restrict__ u,
                                                   h16* __restrict__ q,
                                                   h16* __restrict__ oh,
                                                   float* __restrict__ part0) {
    const int b     = blockIdx.x & 7;
    const int chunk = blockIdx.x >> 3;                  // 0..63
    const int within = chunk * 4096 + threadIdx.x * 16; // 16 consecutive px, row-aligned
    const int pix = b * NPIX + within;
    const int i = within >> 9;
    const int j = within & (WW - 1);

    float of[16];
    #pragma unroll
    for (int s = 0; s < 4; s++) {
        const float4 ov = *(const float4*)(o + pix + 4 * s);
        of[4*s+0] = ov.x; of[4*s+1] = ov.y; of[4*s+2] = ov.z; of[4*s+3] = ov.w;
    }

    half8v oh8[2], uh8[2], qz8[2];
    float urf[16];
    #pragma unroll
    for (int kk = 0; kk < 16; kk++) {
        oh8[kk >> 3][kk & 7] = (h16)of[kk];
        uh8[kk >> 3][kk & 7] = (h16)fast_sigmoid(of[kk]);
        urf[kk] = (float)uh8[kk >> 3][kk & 7];
        qz8[kk >> 3][kk & 7] = (h16)0.f;
    }
    *(half8v*)(u + pix)      = uh8[0];
    *(half8v*)(u + pix + 8)  = uh8[1];
    *(half8v*)(q + pix)      = qz8[0];
    *(half8v*)(q + pix + 8)  = qz8[1];
    *(half8v*)(oh + pix)     = oh8[0];
    *(half8v*)(oh + pix + 8) = oh8[1];

    const float x = (float)(i + 1);
    float s0 = 0.f, sy = 0.f, syy = 0.f;
    #pragma unroll
    for (int kk = 0; kk < 16; kk++) {
        const float y = (float)(j + 1 + kk);
        s0 += urf[kk]; sy += urf[kk] * y; syy += urf[kk] * y * y;
    }
    float v[6] = {s0, x * s0, sy, x * sy, x * x * s0, syy};
    reduce6_store(v, part0 + ((size_t)b * BLK_PER_BATCH + chunk) * 8);
}

// One fused iteration, fp16 state. Each thread computes a 2x8 pixel block:
// rows (ia, ia+1) x cols (jb..jb+7). Row B's "up" divergence term is row A's
// center eval (same formula+inputs). u window: 6 rows x 12 cols for 16 outputs
// (~9 B/px). Eval phase is a fused k-loop (bounded live registers): per k,
// compute conv h-pass + 3 evalF + update, chaining b_left from k-1.
__global__ __launch_bounds__(256) void step_kernel(const h16* __restrict__ oh,
                                                   const h16* __restrict__ uA,
                                                   const h16* __restrict__ qA,
                                                   h16* __restrict__ uB,
                                                   h16* __restrict__ qB,
                                                   const float* __restrict__ partIn,
                                                   float* __restrict__ partOut,
                                                   float* __restrict__ out,
                                                   int lastFlag) {
    const int b    = blockIdx.x & 7;           // batch == XCD -> per-XCD L2 residency
    const int tile = blockIdx.x >> 3;          // 0..63
    const int j0 = (tile & 7) * TX;
    const int i0 = (tile >> 3) * TILE_ROWS;    // 0..448 step 64
    const h16* ubase = uA + (size_t)b * NPIX;
    const h16* qbase = qA + (size_t)b * NPIX;

    const int lin  = threadIdx.x;
    const int lane = lin & 63;
    const int tx = lin & 7;
    const int ty = lin >> 3;                   // 0..31
    const int ia = i0 + 2 * ty;                // row A (even)
    const int jb = j0 + 8 * tx;
    const int loffA = ia * WW + jb;
    const int loffB = loffA + WW;
    const size_t goffA = (size_t)b * NPIX + loffA;
    const size_t goffB = goffA + WW;

    // ======== entry: issue ALL global loads ========
    // partials: 64 slots/batch, exactly one per lane
    const float* P0 = partIn + (size_t)b * (BLK_PER_BATCH * 8) + lane * 8;
    const float4 pA0 = *(const float4*)P0;
    const float4 pB0 = *(const float4*)(P0 + 4);

    // u window: rows ia-2..ia+3, cols jb-2..jb+9, per row: half2 | half8 | half2
    const bool lok = (jb > 0);
    const bool rok = (jb + 8 < WW);
    half2v uL[6]; half8v uM[6]; half2v uR[6];
    #pragma unroll
    for (int r = 0; r < 6; r++) {
        const int ii = ia - 2 + r;
        const bool rowok = (ii >= 0 && ii < HH);
        half2v l; l[0] = (h16)0.f; l[1] = (h16)0.f;
        half8v m;
        #pragma unroll
        for (int c = 0; c < 8; c++) m[c] = (h16)0.f;
        half2v rr; rr[0] = (h16)0.f; rr[1] = (h16)0.f;
        if (rowok) {
            const h16* rowp = ubase + ii * WW;
            m = *(const half8v*)(rowp + jb);
            if (lok) l  = *(const half2v*)(rowp + jb - 2);
            if (rok) rr = *(const half2v*)(rowp + jb + 8);
        }
        uL[r] = l; uM[r] = m; uR[r] = rr;
    }
    // q rows A, B, up(A-1); q-left scalars; o rows A, B
    const half8v qcA8 = *(const half8v*)(qbase + loffA);
    const half8v qcB8 = *(const half8v*)(qbase + loffB);
    const half8v qu8  = *(const half8v*)(qbase + ((ia > 0) ? loffA - WW : loffA));
    const h16    qlAh = qbase[lok ? loffA - 1 : loffA];
    const h16    qlBh = qbase[lok ? loffB - 1 : loffB];
    const half8v oA8  = *(const half8v*)(oh + goffA);
    const half8v oB8  = *(const half8v*)(oh + goffB);

    // ======== per-wave scalar finalize (butterfly, no LDS / no barrier) ========
    float v6[6] = {pA0.x, pA0.y, pA0.z, pA0.w, pB0.x, pB0.y};
    #pragma unroll
    for (int mask = 1; mask < 64; mask <<= 1) {
        #pragma unroll
        for (int c = 0; c < 6; c++) v6[c] += __shfl_xor(v6[c], mask, 64);
    }
    const double sS  = (double)v6[0];
    const double inv = 1.0 / sS;
    const double cxd = (double)v6[1] * inv;
    const double cyd = (double)v6[2] * inv;
    const float cxf    = (float)cxd;
    const float cyf    = (float)cyd;
    const float cossin = (float)((double)v6[3] * inv - cxd * cyd);
    const float bsin   = (float)((double)v6[4] * inv - cxd * cxd);
    const float asin_  = (float)((double)v6[5] * inv - cyd * cyd);

    // ======== streaming v-pass over 6 window rows; keep rows 1..4 cols 1..10 ========
    float vsA[12], vsB[12];
    float Ue[4][10];           // window rows 1..4 (up,A,B,below), cols 1..10
    constexpr float wAr[6] = {W0f, W1f, 1.f, W1f, W0f, 0.f};
    constexpr float wBr[6] = {0.f, W0f, W1f, 1.f, W1f, W0f};
    #pragma unroll
    for (int r = 0; r < 6; r++) {
        float U[12];
        U[0] = (float)uL[r][0]; U[1] = (float)uL[r][1];
        #pragma unroll
        for (int c = 0; c < 8; c++) U[c + 2] = (float)uM[r][c];
        U[10] = (float)uR[r][0]; U[11] = (float)uR[r][1];
        #pragma unroll
        for (int c = 0; c < 12; c++) {
            if (r == 0)             vsA[c] = wAr[0] * U[c];
            else if (wAr[r] != 0.f) vsA[c] += wAr[r] * U[c];
            if (r == 1)             vsB[c] = wBr[1] * U[c];
            else if (wBr[r] != 0.f) vsB[c] += wBr[r] * U[c];
        }
        if (r >= 1 && r <= 4) {
            #pragma unroll
            for (int c = 0; c < 10; c++) Ue[r - 1][c] = U[c + 1];
        }
    }

    const float RiA = edge1d(ia);
    const float RiB = edge1d(ia + 1);
    const float dxA = (float)(ia + 1) - cxf;
    const float dxB = (float)(ia + 2) - cxf;
    const float dxu = (float)ia - cxf;

    // left-boundary evals (col jb-1) for both rows
    float blA = 0.f, blB = 0.f;
    {
        const float dyl = (float)jb - cyf;
        float ad, bl, qd;
        evalF(Ue[1][0], Ue[2][0], Ue[1][1], (float)qlAh,
              dxA, dyl, cossin, bsin, asin_, ad, bl, qd);
        if (lok) blA = bl;
        evalF(Ue[2][0], Ue[3][0], Ue[2][1], (float)qlBh,
              dxB, dyl, cossin, bsin, asin_, ad, bl, qd);
        if (lok) blB = bl;
    }

    // ======== fused k-loop: h-pass + 3 evalF + update per column ========
    half8v uhA, uhB, qhA, qhB;
    float s0A = 0.f, syA = 0.f, syyA = 0.f, s0B = 0.f, syB = 0.f, syyB = 0.f;
    float bA_prev = blA, bB_prev = blB;
    #pragma unroll
    for (int k = 0; k < 8; k++) {
        const float Rj = edge1d(jb + k);
        const float cA = W0f * (vsA[k] + vsA[k + 4]) + W1f * (vsA[k + 1] + vsA[k + 3]) + vsA[k + 2];
        const float cB = W0f * (vsB[k] + vsB[k + 4]) + W1f * (vsB[k + 1] + vsB[k + 3]) + vsB[k + 2];
        const float p4A = INV_NORM * (RiA * Rj - 2.0f * cA);
        const float p4B = INV_NORM * (RiB * Rj - 2.0f * cB);

        const float dy = (float)(jb + k + 1) - cyf;
        float aA, bA, qnA;
        evalF(Ue[1][k + 1], Ue[2][k + 1], Ue[1][k + 2], (float)qcA8[k],
              dxA, dy, cossin, bsin, asin_, aA, bA, qnA);
        float au, bu_d, qu_d;
        evalF(Ue[0][k + 1], Ue[1][k + 1], Ue[0][k + 2], (float)qu8[k],
              dxu, dy, cossin, bsin, asin_, au, bu_d, qu_d);
        const float aUA = (ia > 0) ? au : 0.f;
        float aB, bB, qnB;
        evalF(Ue[2][k + 1], Ue[3][k + 1], Ue[2][k + 2], (float)qcB8[k],
              dxB, dy, cossin, bsin, asin_, aB, bB, qnB);

        const float TqA = aA + bA - aUA - bA_prev;
        const float TqB = aB + bB - aA - bB_prev;    // row B up = row A center
        const float tAv = (float)oA8[k] - p4A - TqA;
        const float tBv = (float)oB8[k] - p4B - TqB;

        uhA[k] = (h16)fast_sigmoid(tAv);
        uhB[k] = (h16)fast_sigmoid(tBv);
        qhA[k] = (h16)qnA;
        qhB[k] = (h16)qnB;

        // sums use the ROUNDED u for field consistency
        const float urA = (float)uhA[k];
        const float urB = (float)uhB[k];
        const float y = (float)(jb + k + 1);
        s0A += urA; syA += urA * y; syyA += urA * y * y;
        s0B += urB; syB += urB * y; syyB += urB * y * y;

        if (lastFlag) {                      // rare path (1 of 50 iterations)
            out[goffA + k] = tAv;
            out[goffB + k] = tBv;
        }
        bA_prev = bA; bB_prev = bB;
    }

    *(half8v*)(uB + goffA) = uhA;
    *(half8v*)(uB + goffB) = uhB;
    *(half8v*)(qB + goffA) = qhA;
    *(half8v*)(qB + goffB) = qhB;
    if (lastFlag) return;                    // no next iteration: partials not needed

    const float xA = (float)(ia + 1);
    const float xB = (float)(ia + 2);
    float v[6] = {s0A + s0B, xA * s0A + xB * s0B, syA + syB,
                  xA * syA + xB * syB, xA * xA * s0A + xB * xB * s0B, syyA + syyB};
    reduce6_store(v, partOut + ((size_t)b * BLK_PER_BATCH + tile) * 8);
}

extern "C" void kernel_launch(void* const* d_in, const int* in_sizes, int n_in,
                              void* d_out, int out_size, void* d_ws, size_t ws_size,
                              hipStream_t stream) {
    const float* o = (const float*)d_in[0];
    float* out = (float*)d_out;

    h16* uA = (h16*)d_ws;
    h16* uB = uA + (size_t)NTOT;
    h16* qA = uB + (size_t)NTOT;
    h16* qB = qA + (size_t)NTOT;
    h16* oh = qB + (size_t)NTOT;
    float* partials = (float*)(oh + (size_t)NTOT);   // 51 iters * 4096 floats

    init_kernel<<<512, 256, 0, stream>>>(o, uA, qA, oh, partials);

    h16 *ua = uA, *ub = uB, *qa = qA, *qb = qB;
    for (int k = 0; k < ITER; k++) {
        step_kernel<<<512, 256, 0, stream>>>(
            oh, ua, qa, ub, qb,
            partials + (size_t)k * PART_ITER_STRIDE,
            partials + (size_t)(k + 1) * PART_ITER_STRIDE,
            out, (k == ITER - 1) ? 1 : 0);
        h16* tmp;
        tmp = ua; ua = ub; ub = tmp;
        tmp = qa; qa = qb; qb = tmp;
    }
}

// Round 8
// 518.803 us; speedup vs baseline: 5.9992x; 1.0079x over previous
//
#include <hip/hip_runtime.h>
#include <math.h>

typedef _Float16 h16;
typedef h16 half8v __attribute__((ext_vector_type(8)));
typedef h16 half4v __attribute__((ext_vector_type(4)));
typedef h16 half2v __attribute__((ext_vector_type(2)));

#define HH 512
#define WW 512
#define BB 8
#define NPIX (HH*WW)        // 262144
#define NTOT (BB*NPIX)      // 2097152
#define ITER 50

#define TX 64               // tile cols
#define TILE_ROWS 64        // tile rows = 32 ty * 2 rows/thread

#define BLK_PER_BATCH 64
#define PART_ITER_STRIDE (BB*BLK_PER_BATCH*8)   // 4096 floats per iteration

// Gaussian 5x5 (sigma=5)
constexpr double W0d = 0.92311634638663587;  // exp(-0.08)
constexpr double W1d = 0.98019867330675525;  // exp(-0.02)
constexpr double SUM1D = 1.0 + 2.0*(W0d + W1d);
constexpr float  INV_NORM = (float)(1.0/(SUM1D*SUM1D + 1e-15));
constexpr float  W0f = (float)W0d;
constexpr float  W1f = (float)W1d;
constexpr float  S1f = (float)SUM1D;

// fast sigmoid: v_exp + v_rcp (1-2 ulp; fp16 state rounding dominates)
__device__ __forceinline__ float fast_sigmoid(float x) {
    const float e = __expf(-x);
    return __builtin_amdgcn_rcpf(1.0f + e);
}

__device__ __forceinline__ float edge1d(int v) {
    float r = S1f;
    if (v == 0 || v == HH - 1) r = S1f - W0f - W1f;
    else if (v == 1 || v == HH - 2) r = S1f - W0f;
    return r;
}

union U32H2 { unsigned u; h16 h[2]; };

// Block-level reduce of 6 floats, one plain store to private partials slot.
// (no atomics, no fences — each block owns its slot)
__device__ __forceinline__ void reduce6_store(float v[6], float* dst8) {
    #pragma unroll
    for (int kk = 0; kk < 6; kk++) {
        float x = v[kk];
        #pragma unroll
        for (int off = 32; off > 0; off >>= 1) x += __shfl_down(x, off, 64);
        v[kk] = x;
    }
    __shared__ float sm[4][6];
    const int lane = threadIdx.x & 63;
    const int wv   = threadIdx.x >> 6;
    if (lane == 0) {
        #pragma unroll
        for (int kk = 0; kk < 6; kk++) sm[wv][kk] = v[kk];
    }
    __syncthreads();
    if (threadIdx.x == 0) {
        float tt[6];
        #pragma unroll
        for (int kk = 0; kk < 6; kk++) tt[kk] = sm[0][kk] + sm[1][kk] + sm[2][kk] + sm[3][kk];
        *(float4*)dst8       = make_float4(tt[0], tt[1], tt[2], tt[3]);
        *(float4*)(dst8 + 4) = make_float4(tt[4], tt[5], 0.f, 0.f);
    }
}

__device__ __forceinline__ void evalF(float uc, float ud, float ur, float qv,
                                      float dx, float dy,
                                      float cossin, float bsin, float asin_,
                                      float& a, float& bv, float& qn) {
    float Tx = -dx * cossin + dy * bsin;
    float Ty =  dy * cossin - dx * asin_;
    const float rn = __builtin_amdgcn_rsqf(Tx * Tx + Ty * Ty + 1e-20f);
    Tx *= rn; Ty *= rn;
    qn = qv - ((ud - uc) * Tx + (ur - uc) * Ty);
    a  = Tx * qn;
    bv = Ty * qn;
}

// u0 = sigmoid(o) (rounded to fp16); q0 = 0; o -> fp16; partials[0] from rounded u.
// 512 blocks x 256 threads x 16 px (one row segment per thread).
__global__ __launch_bounds__(256) void init_kernel(const float* __restrict__ o,
                                                   h16* __restrict__ u,
                                                   h16* __restrict__ q,
                                                   h16* __restrict__ oh,
                                                   float* __restrict__ part0) {
    const int b     = blockIdx.x & 7;
    const int chunk = blockIdx.x >> 3;                  // 0..63
    const int within = chunk * 4096 + threadIdx.x * 16; // 16 consecutive px, row-aligned
    const int pix = b * NPIX + within;
    const int i = within >> 9;
    const int j = within & (WW - 1);

    float of[16];
    #pragma unroll
    for (int s = 0; s < 4; s++) {
        const float4 ov = *(const float4*)(o + pix + 4 * s);
        of[4*s+0] = ov.x; of[4*s+1] = ov.y; of[4*s+2] = ov.z; of[4*s+3] = ov.w;
    }

    half8v oh8[2], uh8[2], qz8[2];
    float urf[16];
    #pragma unroll
    for (int kk = 0; kk < 16; kk++) {
        oh8[kk >> 3][kk & 7] = (h16)of[kk];
        uh8[kk >> 3][kk & 7] = (h16)fast_sigmoid(of[kk]);
        urf[kk] = (float)uh8[kk >> 3][kk & 7];
        qz8[kk >> 3][kk & 7] = (h16)0.f;
    }
    *(half8v*)(u + pix)      = uh8[0];
    *(half8v*)(u + pix + 8)  = uh8[1];
    *(half8v*)(q + pix)      = qz8[0];
    *(half8v*)(q + pix + 8)  = qz8[1];
    *(half8v*)(oh + pix)     = oh8[0];
    *(half8v*)(oh + pix + 8) = oh8[1];

    const float x = (float)(i + 1);
    float s0 = 0.f, sy = 0.f, syy = 0.f;
    #pragma unroll
    for (int kk = 0; kk < 16; kk++) {
        const float y = (float)(j + 1 + kk);
        s0 += urf[kk]; sy += urf[kk] * y; syy += urf[kk] * y * y;
    }
    float v[6] = {s0, x * s0, sy, x * sy, x * x * s0, syy};
    reduce6_store(v, part0 + ((size_t)b * BLK_PER_BATCH + chunk) * 8);
}

// One fused iteration, fp16 state. Each thread computes a 2x8 pixel block.
// Window halos (2 cols each side) come from the NEIGHBOR LANE via __shfl
// instead of global loads (bit-identical values, different transport):
// lane tx's uL = lane tx-1's uM halves 6..7; uR = lane tx+1's uM halves 0..1.
// Only tile-edge lanes (tx==0 / tx==7) load halos from global (exec-masked).
// VMEM/thread: ~13 aligned loads vs ~25 before.
__global__ __launch_bounds__(256) void step_kernel(const h16* __restrict__ oh,
                                                   const h16* __restrict__ uA,
                                                   const h16* __restrict__ qA,
                                                   h16* __restrict__ uB,
                                                   h16* __restrict__ qB,
                                                   const float* __restrict__ partIn,
                                                   float* __restrict__ partOut,
                                                   float* __restrict__ out,
                                                   int lastFlag) {
    const int b    = blockIdx.x & 7;           // batch -> L2 locality
    const int tile = blockIdx.x >> 3;          // 0..63
    const int j0 = (tile & 7) * TX;
    const int i0 = (tile >> 3) * TILE_ROWS;    // 0..448 step 64
    const h16* ubase = uA + (size_t)b * NPIX;
    const h16* qbase = qA + (size_t)b * NPIX;

    const int lin  = threadIdx.x;
    const int lane = lin & 63;
    const int tx = lin & 7;
    const int ty = lin >> 3;                   // 0..31
    const int ia = i0 + 2 * ty;                // row A (even)
    const int jb = j0 + 8 * tx;
    const int loffA = ia * WW + jb;
    const int loffB = loffA + WW;
    const size_t goffA = (size_t)b * NPIX + loffA;
    const size_t goffB = goffA + WW;

    const bool lok = (jb > 0);
    const bool rok = (jb + 8 < WW);
    const bool ltx = (tx > 0);                 // left neighbor lane exists
    const bool rtx = (tx < 7);                 // right neighbor lane exists

    // ======== entry: issue ALL global loads ========
    // partials: 64 slots/batch, exactly one per lane
    const float* P0 = partIn + (size_t)b * (BLK_PER_BATCH * 8) + lane * 8;
    const float4 pA0 = *(const float4*)P0;
    const float4 pB0 = *(const float4*)(P0 + 4);

    // u window: rows ia-2..ia+3. Interior cols via one aligned half8; halo
    // u32s only loaded by tile-edge lanes (2/8 of lanes, exec-masked).
    half8v uM[6];
    unsigned uLbw[6], uRbw[6];
    #pragma unroll
    for (int r = 0; r < 6; r++) {
        const int ii = ia - 2 + r;
        const bool rowok = (ii >= 0 && ii < HH);
        half8v m;
        #pragma unroll
        for (int c = 0; c < 8; c++) m[c] = (h16)0.f;
        unsigned lw = 0u, rw = 0u;
        if (rowok) {
            const h16* rowp = ubase + ii * WW;
            m = *(const half8v*)(rowp + jb);
            if (!ltx && lok) lw = *(const unsigned*)(rowp + jb - 2);
            if (!rtx && rok) rw = *(const unsigned*)(rowp + jb + 8);
        }
        uM[r] = m; uLbw[r] = lw; uRbw[r] = rw;
    }
    // q rows A, B, up(A-1); o rows A, B. q-left via shfl (boundary lanes load).
    const half8v qcA8 = *(const half8v*)(qbase + loffA);
    const half8v qcB8 = *(const half8v*)(qbase + loffB);
    const half8v qu8  = *(const half8v*)(qbase + ((ia > 0) ? loffA - WW : loffA));
    h16 qlA_g = (h16)0.f, qlB_g = (h16)0.f;
    if (!ltx && lok) {
        qlA_g = qbase[loffA - 1];
        qlB_g = qbase[loffB - 1];
    }
    const half8v oA8  = *(const half8v*)(oh + goffA);
    const half8v oB8  = *(const half8v*)(oh + goffB);

    // ======== per-wave scalar finalize (butterfly, no LDS / no barrier) ========
    float v6[6] = {pA0.x, pA0.y, pA0.z, pA0.w, pB0.x, pB0.y};
    #pragma unroll
    for (int mask = 1; mask < 64; mask <<= 1) {
        #pragma unroll
        for (int c = 0; c < 6; c++) v6[c] += __shfl_xor(v6[c], mask, 64);
    }
    const double sS  = (double)v6[0];
    const double inv = 1.0 / sS;
    const double cxd = (double)v6[1] * inv;
    const double cyd = (double)v6[2] * inv;
    const float cxf    = (float)cxd;
    const float cyf    = (float)cyd;
    const float cossin = (float)((double)v6[3] * inv - cxd * cyd);
    const float bsin   = (float)((double)v6[4] * inv - cxd * cxd);
    const float asin_  = (float)((double)v6[5] * inv - cyd * cyd);

    // ======== derive halos from neighbor lanes (wave-level sharing) ========
    unsigned uLw[6], uRw[6];
    #pragma unroll
    for (int r = 0; r < 6; r++) {
        const unsigned w3 = ((const unsigned*)&uM[r])[3];   // halves 6,7
        const unsigned w0 = ((const unsigned*)&uM[r])[0];   // halves 0,1
        const unsigned fromL = (unsigned)__shfl((int)w3, lane - 1, 64);
        const unsigned fromR = (unsigned)__shfl((int)w0, lane + 1, 64);
        uLw[r] = ltx ? fromL : uLbw[r];
        uRw[r] = rtx ? fromR : uRbw[r];
    }
    h16 qlAh, qlBh;
    {
        const unsigned qa3 = ((const unsigned*)&qcA8)[3];
        const unsigned qb3 = ((const unsigned*)&qcB8)[3];
        U32H2 ca, cb;
        ca.u = (unsigned)__shfl((int)qa3, lane - 1, 64);
        cb.u = (unsigned)__shfl((int)qb3, lane - 1, 64);
        qlAh = ltx ? ca.h[1] : qlA_g;      // neighbor's col jb-1 (half index 7)
        qlBh = ltx ? cb.h[1] : qlB_g;
    }

    // ======== streaming v-pass over 6 window rows; keep rows 1..4 cols 1..10 ========
    float vsA[12], vsB[12];
    float Ue[4][10];           // window rows 1..4 (up,A,B,below), cols 1..10
    constexpr float wAr[6] = {W0f, W1f, 1.f, W1f, W0f, 0.f};
    constexpr float wBr[6] = {0.f, W0f, W1f, 1.f, W1f, W0f};
    #pragma unroll
    for (int r = 0; r < 6; r++) {
        float U[12];
        U32H2 cl, cr;
        cl.u = uLw[r]; cr.u = uRw[r];
        U[0] = (float)cl.h[0]; U[1] = (float)cl.h[1];
        #pragma unroll
        for (int c = 0; c < 8; c++) U[c + 2] = (float)uM[r][c];
        U[10] = (float)cr.h[0]; U[11] = (float)cr.h[1];
        #pragma unroll
        for (int c = 0; c < 12; c++) {
            if (r == 0)             vsA[c] = wAr[0] * U[c];
            else if (wAr[r] != 0.f) vsA[c] += wAr[r] * U[c];
            if (r == 1)             vsB[c] = wBr[1] * U[c];
            else if (wBr[r] != 0.f) vsB[c] += wBr[r] * U[c];
        }
        if (r >= 1 && r <= 4) {
            #pragma unroll
            for (int c = 0; c < 10; c++) Ue[r - 1][c] = U[c + 1];
        }
    }

    const float RiA = edge1d(ia);
    const float RiB = edge1d(ia + 1);
    const float dxA = (float)(ia + 1) - cxf;
    const float dxB = (float)(ia + 2) - cxf;
    const float dxu = (float)ia - cxf;

    // left-boundary evals (col jb-1) for both rows
    float blA = 0.f, blB = 0.f;
    {
        const float dyl = (float)jb - cyf;
        float ad, bl, qd;
        evalF(Ue[1][0], Ue[2][0], Ue[1][1], (float)qlAh,
              dxA, dyl, cossin, bsin, asin_, ad, bl, qd);
        if (lok) blA = bl;
        evalF(Ue[2][0], Ue[3][0], Ue[2][1], (float)qlBh,
              dxB, dyl, cossin, bsin, asin_, ad, bl, qd);
        if (lok) blB = bl;
    }

    // ======== fused k-loop: h-pass + 3 evalF + update per column ========
    half8v uhA, uhB, qhA, qhB;
    float s0A = 0.f, syA = 0.f, syyA = 0.f, s0B = 0.f, syB = 0.f, syyB = 0.f;
    float bA_prev = blA, bB_prev = blB;
    #pragma unroll
    for (int k = 0; k < 8; k++) {
        const float Rj = edge1d(jb + k);
        const float cA = W0f * (vsA[k] + vsA[k + 4]) + W1f * (vsA[k + 1] + vsA[k + 3]) + vsA[k + 2];
        const float cB = W0f * (vsB[k] + vsB[k + 4]) + W1f * (vsB[k + 1] + vsB[k + 3]) + vsB[k + 2];
        const float p4A = INV_NORM * (RiA * Rj - 2.0f * cA);
        const float p4B = INV_NORM * (RiB * Rj - 2.0f * cB);

        const float dy = (float)(jb + k + 1) - cyf;
        float aA, bA, qnA;
        evalF(Ue[1][k + 1], Ue[2][k + 1], Ue[1][k + 2], (float)qcA8[k],
              dxA, dy, cossin, bsin, asin_, aA, bA, qnA);
        float au, bu_d, qu_d;
        evalF(Ue[0][k + 1], Ue[1][k + 1], Ue[0][k + 2], (float)qu8[k],
              dxu, dy, cossin, bsin, asin_, au, bu_d, qu_d);
        const float aUA = (ia > 0) ? au : 0.f;
        float aB, bB, qnB;
        evalF(Ue[2][k + 1], Ue[3][k + 1], Ue[2][k + 2], (float)qcB8[k],
              dxB, dy, cossin, bsin, asin_, aB, bB, qnB);

        const float TqA = aA + bA - aUA - bA_prev;
        const float TqB = aB + bB - aA - bB_prev;    // row B up = row A center
        const float tAv = (float)oA8[k] - p4A - TqA;
        const float tBv = (float)oB8[k] - p4B - TqB;

        uhA[k] = (h16)fast_sigmoid(tAv);
        uhB[k] = (h16)fast_sigmoid(tBv);
        qhA[k] = (h16)qnA;
        qhB[k] = (h16)qnB;

        // sums use the ROUNDED u for field consistency
        const float urA = (float)uhA[k];
        const float urB = (float)uhB[k];
        const float y = (float)(jb + k + 1);
        s0A += urA; syA += urA * y; syyA += urA * y * y;
        s0B += urB; syB += urB * y; syyB += urB * y * y;

        if (lastFlag) {                      // rare path (1 of 50 iterations)
            out[goffA + k] = tAv;
            out[goffB + k] = tBv;
        }
        bA_prev = bA; bB_prev = bB;
    }

    *(half8v*)(uB + goffA) = uhA;
    *(half8v*)(uB + goffB) = uhB;
    *(half8v*)(qB + goffA) = qhA;
    *(half8v*)(qB + goffB) = qhB;
    if (lastFlag) return;                    // no next iteration: partials not needed

    const float xA = (float)(ia + 1);
    const float xB = (float)(ia + 2);
    float v[6] = {s0A + s0B, xA * s0A + xB * s0B, syA + syB,
                  xA * syA + xB * syB, xA * xA * s0A + xB * xB * s0B, syyA + syyB};
    reduce6_store(v, partOut + ((size_t)b * BLK_PER_BATCH + tile) * 8);
}

extern "C" void kernel_launch(void* const* d_in, const int* in_sizes, int n_in,
                              void* d_out, int out_size, void* d_ws, size_t ws_size,
                              hipStream_t stream) {
    const float* o = (const float*)d_in[0];
    float* out = (float*)d_out;

    h16* uA = (h16*)d_ws;
    h16* uB = uA + (size_t)NTOT;
    h16* qA = uB + (size_t)NTOT;
    h16* qB = qA + (size_t)NTOT;
    h16* oh = qB + (size_t)NTOT;
    float* partials = (float*)(oh + (size_t)NTOT);   // 51 iters * 4096 floats

    init_kernel<<<512, 256, 0, stream>>>(o, uA, qA, oh, partials);

    h16 *ua = uA, *ub = uB, *qa = qA, *qb = qB;
    for (int k = 0; k < ITER; k++) {
        step_kernel<<<512, 256, 0, stream>>>(
            oh, ua, qa, ub, qb,
            partials + (size_t)k * PART_ITER_STRIDE,
            partials + (size_t)(k + 1) * PART_ITER_STRIDE,
            out, (k == ITER - 1) ? 1 : 0);
        h16* tmp;
        tmp = ua; ua = ub; ub = tmp;
        tmp = qa; qa = qb; qb = tmp;
    }
}